// Round 4
// baseline (2036.240 us; speedup 1.0000x reference)
//
#include <hip/hip_runtime.h>
#include <stdint.h>

// ---------------- problem constants ----------------
#define NN 100000          // nodes
#define EE 3200000         // raw edges
#define NEDGE (EE + NN)    // + self loops
#define KD 745             // F_IN
#define GKP 768            // K padded to mult of 32
#define HD 128             // hidden
#define NC 8               // classes

// bucket sort params
#define BS 256             // nodes per bucket
#define NBK 391            // ceil(NN/BS)
#define CAP 10240          // max edges per bucket (mean 8448, sigma ~92 -> 20 sigma slack)

typedef unsigned short ushort_t;
typedef __attribute__((ext_vector_type(8))) short short8;
typedef __attribute__((ext_vector_type(4))) float f32x4;

__device__ __forceinline__ ushort_t f2bf(float f) {
  unsigned int u = __float_as_uint(f);
  u += 0x7FFFu + ((u >> 16) & 1u);     // RNE
  return (ushort_t)(u >> 16);
}
__device__ __forceinline__ float bf2f(ushort_t h) {
  return __uint_as_float(((unsigned int)h) << 16);
}
__device__ __forceinline__ float lrelu_exp(float t) {
  return __expf(t >= 0.f ? t : 0.2f * t);
}

// -------- detect whether edge_index arrived as int64 (odd int32 words all 0) --------
__global__ void k_detect(const int* __restrict__ ei, int* __restrict__ flag) {
  if (threadIdx.x == 0) {
    int orv = 0;
    #pragma unroll
    for (int i = 0; i < 16; i++) orv |= ei[2 * i + 1];
    flag[0] = (orv == 0) ? 1 : 0;
  }
}

__device__ __forceinline__ void edge_sd(const int* __restrict__ ei, int flag, int e,
                                        int& s, int& d) {
  if (e < EE) {
    if (flag) {
      s = ((const int2*)ei)[e].x;
      d = ((const int2*)ei)[EE + e].x;
    } else {
      s = ei[e];
      d = ei[EE + e];
    }
  } else { s = e - EE; d = s; }
}

// -------- W1 -> transposed bf16 hi/lo, K padded to 768 --------
__global__ __launch_bounds__(256)
void k_prepw1(const float* __restrict__ W1, ushort_t* __restrict__ WhiT,
              ushort_t* __restrict__ WloT) {
  int idx = blockIdx.x * 256 + threadIdx.x;       // 128*768 total
  if (idx >= HD * GKP) return;
  int n = idx / GKP, k = idx % GKP;
  float v = (k < KD) ? W1[(size_t)k * HD + n] : 0.f;
  ushort_t hi = f2bf(v);
  ushort_t lo = f2bf(v - bf2f(hi));
  WhiT[(size_t)n * GKP + k] = hi;
  WloT[(size_t)n * GKP + k] = lo;
}

// -------- GEMM1: h1[N,128] = x[N,745] @ W1 ; bf16 MFMA, 3-term split --------
__global__ __launch_bounds__(256, 2)
void k_gemm1(const float* __restrict__ x, const ushort_t* __restrict__ WhiT,
             const ushort_t* __restrict__ WloT, float* __restrict__ h1) {
  __shared__ ushort_t Ah[128 * 32], Al[128 * 32], Bh[128 * 32], Bl[128 * 32];
  const int tid = threadIdx.x;
  const int lane = tid & 63;
  const int wid = tid >> 6;
  const int wr = wid >> 1, wc = wid & 1;          // 2x2 waves over 128x128 tile
  const long long row0 = (long long)blockIdx.x * 128;
  const int am = tid >> 1, ah = tid & 1;          // A stage: row am, 16 floats

  f32x4 acc[4][4];
  #pragma unroll
  for (int i = 0; i < 4; i++)
    #pragma unroll
    for (int j = 0; j < 4; j++) acc[i][j] = (f32x4){0.f, 0.f, 0.f, 0.f};

  for (int k0 = 0; k0 < GKP; k0 += 32) {
    // ---- stage A (fp32 -> bf16 hi/lo) ----
    {
      long long gr = row0 + am;
      int kb = k0 + ah * 16;
      float v[16];
      if (gr < NN && kb + 16 <= KD) {
        const float* xp = x + gr * KD + kb;
        #pragma unroll
        for (int i = 0; i < 16; i++) v[i] = xp[i];
      } else if (gr < NN) {
        const float* xp = x + gr * KD + kb;
        #pragma unroll
        for (int i = 0; i < 16; i++) v[i] = (kb + i < KD) ? xp[i] : 0.f;
      } else {
        #pragma unroll
        for (int i = 0; i < 16; i++) v[i] = 0.f;
      }
      ushort_t* ph = &Ah[am * 32 + ah * 16];
      ushort_t* pl = &Al[am * 32 + ah * 16];
      #pragma unroll
      for (int i = 0; i < 16; i++) {
        ushort_t hi = f2bf(v[i]);
        ph[i] = hi;
        pl[i] = f2bf(v[i] - bf2f(hi));
      }
    }
    // ---- stage B (already bf16, [n][k] rows) ----
    {
      const int bn = tid >> 1, off = (tid & 1) * 16;
      const ushort_t* gh = WhiT + (size_t)bn * GKP + k0 + off;
      const ushort_t* gl = WloT + (size_t)bn * GKP + k0 + off;
      ushort_t* dh = &Bh[bn * 32 + off];
      ushort_t* dl = &Bl[bn * 32 + off];
      *(short8*)dh = *(const short8*)gh;
      *(short8*)(dh + 8) = *(const short8*)(gh + 8);
      *(short8*)dl = *(const short8*)gl;
      *(short8*)(dl + 8) = *(const short8*)(gl + 8);
    }
    __syncthreads();

    const int rr = lane & 15, kk = (lane >> 4) * 8;
    short8 a_h[4], a_l[4], b_h[4], b_l[4];
    #pragma unroll
    for (int i = 0; i < 4; i++) {
      a_h[i] = *(const short8*)&Ah[(wr * 64 + i * 16 + rr) * 32 + kk];
      a_l[i] = *(const short8*)&Al[(wr * 64 + i * 16 + rr) * 32 + kk];
      b_h[i] = *(const short8*)&Bh[(wc * 64 + i * 16 + rr) * 32 + kk];
      b_l[i] = *(const short8*)&Bl[(wc * 64 + i * 16 + rr) * 32 + kk];
    }
    #pragma unroll
    for (int i = 0; i < 4; i++)
      #pragma unroll
      for (int j = 0; j < 4; j++) {
        acc[i][j] = __builtin_amdgcn_mfma_f32_16x16x32_bf16(a_h[i], b_h[j], acc[i][j], 0, 0, 0);
        acc[i][j] = __builtin_amdgcn_mfma_f32_16x16x32_bf16(a_h[i], b_l[j], acc[i][j], 0, 0, 0);
        acc[i][j] = __builtin_amdgcn_mfma_f32_16x16x32_bf16(a_l[i], b_h[j], acc[i][j], 0, 0, 0);
      }
    __syncthreads();
  }
  // epilogue: D col=lane&15, row=(lane>>4)*4+r  [m89-verified]
  #pragma unroll
  for (int i = 0; i < 4; i++)
    #pragma unroll
    for (int j = 0; j < 4; j++)
      #pragma unroll
      for (int r = 0; r < 4; r++) {
        long long grow = row0 + wr * 64 + i * 16 + (lane >> 4) * 4 + r;
        int gcol = wc * 64 + j * 16 + (lane & 15);
        if (grow < NN) h1[grow * HD + gcol] = acc[i][j][r];
      }
}

// -------- per-node attention logits, layer 1: s = h1 . a  --------
__global__ __launch_bounds__(256)
void k_s1(const float* __restrict__ h1, const float* __restrict__ as_,
          const float* __restrict__ ad_, float* __restrict__ s1s,
          float* __restrict__ s1d) {
  int w = threadIdx.x >> 6, lane = threadIdx.x & 63;
  int n = blockIdx.x * 4 + w;
  if (n >= NN) return;
  const float* hp = h1 + (size_t)n * HD;
  float h0 = hp[lane], h1v = hp[lane + 64];
  float ps = h0 * as_[lane] + h1v * as_[lane + 64];
  float pd = h0 * ad_[lane] + h1v * ad_[lane + 64];
  #pragma unroll
  for (int m = 32; m; m >>= 1) {
    ps += __shfl_xor(ps, m, 64);
    pd += __shfl_xor(pd, m, 64);
  }
  if (lane == 0) { s1s[n] = ps; s1d[n] = pd; }
}

// -------- phase 1: bucket-partition edges --------
// pairs[b*CAP + i] = src | (dst&255)<<17  for edges with dst>>8 == b
__global__ __launch_bounds__(256)
void k_part1(const int* __restrict__ ei, const int* __restrict__ flagp,
             int* __restrict__ bfill, int* __restrict__ pairs) {
  const int flag = flagp[0];
  int stride = gridDim.x * blockDim.x;
  for (int e = blockIdx.x * blockDim.x + threadIdx.x; e < NEDGE; e += stride) {
    int s, d;
    edge_sd(ei, flag, e, s, d);
    int b = d >> 8;
    int p = s | ((d & 255) << 17);
    int pos = atomicAdd(&bfill[b], 1);
    if (pos < CAP) pairs[b * CAP + pos] = p;   // clamp guard (cannot trip on this data)
  }
}

// -------- scan bucket counts -> bbase[0..NBK] --------
__global__ __launch_bounds__(256)
void k_bscan(const int* __restrict__ bfill, int* __restrict__ bbase) {
  __shared__ int sm[512];
  int t = threadIdx.x;
  for (int i = t; i < 512; i += 256) {
    int v = (i < NBK) ? bfill[i] : 0;
    sm[i] = v < CAP ? v : CAP;
  }
  __syncthreads();
  for (int d = 1; d < 512; d <<= 1) {
    int v0 = (t >= d) ? sm[t - d] : 0;
    int v1 = sm[t + 256 - d];
    __syncthreads();
    sm[t] += v0;
    sm[t + 256] += v1;
    __syncthreads();
  }
  for (int i = t; i <= NBK; i += 256) bbase[i] = (i == 0) ? 0 : sm[i - 1];
}

// -------- phase 2: per-bucket local count/scan/place; writes rp and adj --------
__global__ __launch_bounds__(256)
void k_part2(const int* __restrict__ pairs, const int* __restrict__ bfill,
             const int* __restrict__ bbase, int* __restrict__ rp,
             int* __restrict__ adj) {
  __shared__ int cnt[BS], fillv[BS], wsum[4];
  int b = blockIdx.x, t = threadIdx.x;
  int n0 = b * BS;
  int j0 = bbase[b];
  int ne = bfill[b]; ne = ne < CAP ? ne : CAP;
  const int* pb = pairs + (size_t)b * CAP;
  cnt[t] = 0;
  __syncthreads();
  for (int j = t; j < ne; j += 256)
    atomicAdd(&cnt[((unsigned)pb[j]) >> 17], 1);
  __syncthreads();
  // exclusive scan over the 256 counts
  int lane = t & 63, w = t >> 6;
  int v = cnt[t];
  int xv = v;
  #pragma unroll
  for (int d = 1; d < 64; d <<= 1) {
    int y = __shfl_up(xv, d, 64);
    if (lane >= d) xv += y;
  }
  if (lane == 63) wsum[w] = xv;
  __syncthreads();
  int woff = 0;
  #pragma unroll
  for (int i = 0; i < 4; i++) if (i < w) woff += wsum[i];
  int excl = j0 + woff + xv - v;
  if (n0 + t < NN) rp[n0 + t] = excl;
  fillv[t] = excl;
  __syncthreads();
  for (int j = t; j < ne; j += 256) {
    int p = pb[j];
    int pos = atomicAdd(&fillv[((unsigned)p) >> 17], 1);
    adj[pos] = p & 0x1FFFF;
  }
  if (b == 0 && t == 0) rp[NN] = NEDGE;
}

// -------- layer-1 aggregation fused with layer-2 projection --------
// x2 = relu( (1/den) * sum_j exp(lrelu(ss[s]+sd[n])) * h1[s] + b1 )  (den inline)
// h2 = x2 @ W2 ; s2s/s2d = h2 . a2_{src,dst}     (x2 never materialized)
__global__ __launch_bounds__(256)
void k_agg1h2(const float* __restrict__ h1, const int* __restrict__ adj,
              const int* __restrict__ rp, const float* __restrict__ s1s,
              const float* __restrict__ s1d, const float* __restrict__ b1,
              const float* __restrict__ W2, const float* __restrict__ a2s,
              const float* __restrict__ a2d, float* __restrict__ h2,
              float* __restrict__ s2s, float* __restrict__ s2d) {
  __shared__ float W2T[NC * HD];     // transposed [k][f] for conflict-light f32x4 reads
  int t = threadIdx.x;
  for (int i = t; i < HD * NC; i += 256) {
    int f = i >> 3, k = i & 7;       // W2 is [f][k]
    W2T[k * HD + f] = W2[i];
  }
  __syncthreads();
  int wv = t >> 6, lane = t & 63;
  int n = blockIdx.x * 4 + wv;
  if (n >= NN) return;
  int half = lane >> 5, l32 = lane & 31;
  int j0 = rp[n], j1 = rp[n + 1];
  int deg = j1 - j0;
  int dh = (deg + 1) >> 1;
  int js = half ? (j0 + dh) : j0;
  int je = half ? j1 : (j0 + dh);
  float sdv = s1d[n];
  f32x4 acc = (f32x4){0.f, 0.f, 0.f, 0.f};
  float dsum = 0.f;
  int j = js;
  for (; j + 4 <= je; j += 4) {              // 4 gathers in flight per half-wave
    int e0 = adj[j], e1 = adj[j + 1], e2 = adj[j + 2], e3 = adj[j + 3];
    f32x4 v0 = *(const f32x4*)(h1 + (size_t)e0 * HD + l32 * 4);
    f32x4 v1 = *(const f32x4*)(h1 + (size_t)e1 * HD + l32 * 4);
    f32x4 v2 = *(const f32x4*)(h1 + (size_t)e2 * HD + l32 * 4);
    f32x4 v3 = *(const f32x4*)(h1 + (size_t)e3 * HD + l32 * 4);
    float w0 = lrelu_exp(s1s[e0] + sdv);
    float w1 = lrelu_exp(s1s[e1] + sdv);
    float w2 = lrelu_exp(s1s[e2] + sdv);
    float w3 = lrelu_exp(s1s[e3] + sdv);
    acc += w0 * v0; acc += w1 * v1; acc += w2 * v2; acc += w3 * v3;
    dsum += (w0 + w1) + (w2 + w3);
  }
  for (; j < je; ++j) {
    int e0 = adj[j];
    f32x4 v0 = *(const f32x4*)(h1 + (size_t)e0 * HD + l32 * 4);
    float w0 = lrelu_exp(s1s[e0] + sdv);
    acc += w0 * v0; dsum += w0;
  }
  // combine the two half-wave partial sums (features identical across halves)
  #pragma unroll
  for (int c = 0; c < 4; c++) acc[c] += __shfl_xor(acc[c], 32, 64);
  dsum += __shfl_xor(dsum, 32, 64);
  float inv = 1.f / (dsum + 1e-16f);
  f32x4 bv = *(const f32x4*)(b1 + l32 * 4);
  f32x4 x2v;
  #pragma unroll
  for (int c = 0; c < 4; c++) {
    float r = acc[c] * inv + bv[c];
    x2v[c] = r > 0.f ? r : 0.f;
  }
  // h2 = x2 @ W2 (per-lane 4-feature partial, then 32-lane reduce)
  float hk[NC];
  #pragma unroll
  for (int k = 0; k < NC; k++) {
    f32x4 wv4 = *(const f32x4*)&W2T[k * HD + l32 * 4];
    hk[k] = x2v[0] * wv4[0] + x2v[1] * wv4[1] + x2v[2] * wv4[2] + x2v[3] * wv4[3];
  }
  #pragma unroll
  for (int m = 1; m < 32; m <<= 1)
    #pragma unroll
    for (int k = 0; k < NC; k++) hk[k] += __shfl_xor(hk[k], m, 64);
  if (lane == 0) {
    float ss = 0.f, sd = 0.f;
    #pragma unroll
    for (int k = 0; k < NC; k++) {
      h2[(size_t)n * NC + k] = hk[k];
      ss += hk[k] * a2s[k];
      sd += hk[k] * a2d[k];
    }
    s2s[n] = ss;
    s2d[n] = sd;
  }
}

// -------- layer-2 aggregation: wave per node, 8 edges x 8 feats in flight --------
__global__ __launch_bounds__(256)
void k_agg2(const float* __restrict__ h2, const int* __restrict__ adj,
            const int* __restrict__ rp, const float* __restrict__ s2s,
            const float* __restrict__ s2d, const float* __restrict__ b2,
            float* __restrict__ out) {
  int wv = threadIdx.x >> 6, lane = threadIdx.x & 63;
  int n = blockIdx.x * 4 + wv;
  if (n >= NN) return;
  int sub = lane >> 3, k = lane & 7;
  int j0 = rp[n], j1 = rp[n + 1];
  float sdv = s2d[n];
  float a = 0.f, dsum = 0.f;
  for (int j = j0 + sub; j < j1; j += 8) {
    int s = adj[j];
    float wvv = lrelu_exp(s2s[s] + sdv);
    a += wvv * h2[(size_t)s * NC + k];
    dsum += wvv;
  }
  #pragma unroll
  for (int m = 8; m < 64; m <<= 1) {
    a += __shfl_xor(a, m, 64);
    dsum += __shfl_xor(dsum, m, 64);
  }
  if (sub == 0) out[(size_t)n * NC + k] = a / (dsum + 1e-16f) + b2[k];
}

extern "C" void kernel_launch(void* const* d_in, const int* in_sizes, int n_in,
                              void* d_out, int out_size, void* d_ws, size_t ws_size,
                              hipStream_t stream) {
  (void)in_sizes; (void)n_in; (void)out_size;
  const float* x   = (const float*)d_in[0];
  const int*   ei  = (const int*)d_in[1];
  const float* W1  = (const float*)d_in[2];
  const float* a1s = (const float*)d_in[3];
  const float* a1d = (const float*)d_in[4];
  const float* b1  = (const float*)d_in[5];
  const float* W2  = (const float*)d_in[6];
  const float* a2s = (const float*)d_in[7];
  const float* a2d = (const float*)d_in[8];
  const float* b2  = (const float*)d_in[9];
  float* out = (float*)d_out;
  char* ws = (char*)d_ws;

  // ---- workspace layout (bytes), 256-aligned ----
  size_t o = 0;
  auto take = [&](size_t bytes) { size_t c = o; o += (bytes + 255) & ~(size_t)255; return c; };
  size_t o_flag  = take(64);
  size_t o_whi   = take((size_t)HD * GKP * 2);
  size_t o_wlo   = take((size_t)HD * GKP * 2);
  size_t o_h1    = take((size_t)NN * HD * 4);
  size_t o_h2    = take((size_t)NN * NC * 4);
  size_t o_s1s   = take((size_t)NN * 4);
  size_t o_s1d   = take((size_t)NN * 4);
  size_t o_s2s   = take((size_t)NN * 4);
  size_t o_s2d   = take((size_t)NN * 4);
  size_t o_rp    = take((size_t)(NN + 1) * 4);
  size_t o_adj   = take((size_t)NEDGE * 4);
  size_t o_pairs = take((size_t)NBK * CAP * 4);
  size_t o_bbase = take((size_t)(NBK + 1) * 4);
  size_t o_bfill = take((size_t)(NBK + 1) * 4);   // memset to 0 each call
  if (o > ws_size) return;                        // workspace too small -> loud failure

  int*   flag = (int*)(ws + o_flag);
  ushort_t* whi = (ushort_t*)(ws + o_whi);
  ushort_t* wlo = (ushort_t*)(ws + o_wlo);
  float* h1  = (float*)(ws + o_h1);
  float* h2  = (float*)(ws + o_h2);
  float* s1s = (float*)(ws + o_s1s);
  float* s1d = (float*)(ws + o_s1d);
  float* s2s = (float*)(ws + o_s2s);
  float* s2d = (float*)(ws + o_s2d);
  int* rp    = (int*)(ws + o_rp);
  int* adj   = (int*)(ws + o_adj);
  int* pairs = (int*)(ws + o_pairs);
  int* bbase = (int*)(ws + o_bbase);
  int* bfill = (int*)(ws + o_bfill);

  hipMemsetAsync(bfill, 0, (size_t)(NBK + 1) * 4, stream);
  k_detect<<<1, 64, 0, stream>>>(ei, flag);
  k_prepw1<<<(HD * GKP + 255) / 256, 256, 0, stream>>>(W1, whi, wlo);
  k_gemm1<<<(NN + 127) / 128, 256, 0, stream>>>(x, whi, wlo, h1);
  k_s1<<<(NN + 3) / 4, 256, 0, stream>>>(h1, a1s, a1d, s1s, s1d);
  k_part1<<<2048, 256, 0, stream>>>(ei, flag, bfill, pairs);
  k_bscan<<<1, 256, 0, stream>>>(bfill, bbase);
  k_part2<<<NBK, 256, 0, stream>>>(pairs, bfill, bbase, rp, adj);
  k_agg1h2<<<(NN + 3) / 4, 256, 0, stream>>>(h1, adj, rp, s1s, s1d, b1, W2,
                                             a2s, a2d, h2, s2s, s2d);
  k_agg2<<<(NN + 3) / 4, 256, 0, stream>>>(h2, adj, rp, s2s, s2d, b2, out);
}

// Round 5
// 891.407 us; speedup vs baseline: 2.2843x; 2.2843x over previous
//
#include <hip/hip_runtime.h>
#include <stdint.h>

// ---------------- problem constants ----------------
#define NN 100000          // nodes
#define EE 3200000         // raw edges
#define NEDGE (EE + NN)    // + self loops
#define KD 745             // F_IN
#define GKP 768            // K padded to mult of 32
#define HD 128             // hidden
#define NC 8               // classes

// partition params
#define BS 256                       // nodes per bucket
#define NBK 391                      // ceil(NN/BS)
#define NBLK 784                     // histogram/placement blocks
#define CHUNK ((NEDGE + NBLK - 1) / NBLK)

typedef unsigned short ushort_t;
typedef __attribute__((ext_vector_type(8))) short short8;
typedef __attribute__((ext_vector_type(4))) float f32x4;

__device__ __forceinline__ ushort_t f2bf(float f) {
  unsigned int u = __float_as_uint(f);
  u += 0x7FFFu + ((u >> 16) & 1u);     // RNE
  return (ushort_t)(u >> 16);
}
__device__ __forceinline__ float bf2f(ushort_t h) {
  return __uint_as_float(((unsigned int)h) << 16);
}
__device__ __forceinline__ float lrelu_exp(float t) {
  return __expf(t >= 0.f ? t : 0.2f * t);
}

// -------- detect whether edge_index arrived as int64 (odd int32 words all 0) --------
__global__ void k_detect(const int* __restrict__ ei, int* __restrict__ flag) {
  if (threadIdx.x == 0) {
    int orv = 0;
    #pragma unroll
    for (int i = 0; i < 16; i++) orv |= ei[2 * i + 1];
    flag[0] = (orv == 0) ? 1 : 0;
  }
}

__device__ __forceinline__ void edge_sd(const int* __restrict__ ei, int flag, int e,
                                        int& s, int& d) {
  if (e < EE) {
    if (flag) {
      s = ((const int2*)ei)[e].x;
      d = ((const int2*)ei)[EE + e].x;
    } else {
      s = ei[e];
      d = ei[EE + e];
    }
  } else { s = e - EE; d = s; }
}

// -------- W1 -> transposed bf16 hi/lo, K padded to 768 --------
__global__ __launch_bounds__(256)
void k_prepw1(const float* __restrict__ W1, ushort_t* __restrict__ WhiT,
              ushort_t* __restrict__ WloT) {
  int idx = blockIdx.x * 256 + threadIdx.x;       // 128*768 total
  if (idx >= HD * GKP) return;
  int n = idx / GKP, k = idx % GKP;
  float v = (k < KD) ? W1[(size_t)k * HD + n] : 0.f;
  ushort_t hi = f2bf(v);
  ushort_t lo = f2bf(v - bf2f(hi));
  WhiT[(size_t)n * GKP + k] = hi;
  WloT[(size_t)n * GKP + k] = lo;
}

// -------- GEMM1: h1[N,128] = x[N,745] @ W1 ; bf16 MFMA, 3-term split --------
__global__ __launch_bounds__(256, 2)
void k_gemm1(const float* __restrict__ x, const ushort_t* __restrict__ WhiT,
             const ushort_t* __restrict__ WloT, float* __restrict__ h1) {
  __shared__ ushort_t Ah[128 * 32], Al[128 * 32], Bh[128 * 32], Bl[128 * 32];
  const int tid = threadIdx.x;
  const int lane = tid & 63;
  const int wid = tid >> 6;
  const int wr = wid >> 1, wc = wid & 1;          // 2x2 waves over 128x128 tile
  const long long row0 = (long long)blockIdx.x * 128;
  const int am = tid >> 1, ah = tid & 1;          // A stage: row am, 16 floats

  f32x4 acc[4][4];
  #pragma unroll
  for (int i = 0; i < 4; i++)
    #pragma unroll
    for (int j = 0; j < 4; j++) acc[i][j] = (f32x4){0.f, 0.f, 0.f, 0.f};

  for (int k0 = 0; k0 < GKP; k0 += 32) {
    // ---- stage A (fp32 -> bf16 hi/lo) ----
    {
      long long gr = row0 + am;
      int kb = k0 + ah * 16;
      float v[16];
      if (gr < NN && kb + 16 <= KD) {
        const float* xp = x + gr * KD + kb;
        #pragma unroll
        for (int i = 0; i < 16; i++) v[i] = xp[i];
      } else if (gr < NN) {
        const float* xp = x + gr * KD + kb;
        #pragma unroll
        for (int i = 0; i < 16; i++) v[i] = (kb + i < KD) ? xp[i] : 0.f;
      } else {
        #pragma unroll
        for (int i = 0; i < 16; i++) v[i] = 0.f;
      }
      ushort_t* ph = &Ah[am * 32 + ah * 16];
      ushort_t* pl = &Al[am * 32 + ah * 16];
      #pragma unroll
      for (int i = 0; i < 16; i++) {
        ushort_t hi = f2bf(v[i]);
        ph[i] = hi;
        pl[i] = f2bf(v[i] - bf2f(hi));
      }
    }
    // ---- stage B (already bf16, [n][k] rows) ----
    {
      const int bn = tid >> 1, off = (tid & 1) * 16;
      const ushort_t* gh = WhiT + (size_t)bn * GKP + k0 + off;
      const ushort_t* gl = WloT + (size_t)bn * GKP + k0 + off;
      ushort_t* dh = &Bh[bn * 32 + off];
      ushort_t* dl = &Bl[bn * 32 + off];
      *(short8*)dh = *(const short8*)gh;
      *(short8*)(dh + 8) = *(const short8*)(gh + 8);
      *(short8*)dl = *(const short8*)gl;
      *(short8*)(dl + 8) = *(const short8*)(gl + 8);
    }
    __syncthreads();

    const int rr = lane & 15, kk = (lane >> 4) * 8;
    short8 a_h[4], a_l[4], b_h[4], b_l[4];
    #pragma unroll
    for (int i = 0; i < 4; i++) {
      a_h[i] = *(const short8*)&Ah[(wr * 64 + i * 16 + rr) * 32 + kk];
      a_l[i] = *(const short8*)&Al[(wr * 64 + i * 16 + rr) * 32 + kk];
      b_h[i] = *(const short8*)&Bh[(wc * 64 + i * 16 + rr) * 32 + kk];
      b_l[i] = *(const short8*)&Bl[(wc * 64 + i * 16 + rr) * 32 + kk];
    }
    #pragma unroll
    for (int i = 0; i < 4; i++)
      #pragma unroll
      for (int j = 0; j < 4; j++) {
        acc[i][j] = __builtin_amdgcn_mfma_f32_16x16x32_bf16(a_h[i], b_h[j], acc[i][j], 0, 0, 0);
        acc[i][j] = __builtin_amdgcn_mfma_f32_16x16x32_bf16(a_h[i], b_l[j], acc[i][j], 0, 0, 0);
        acc[i][j] = __builtin_amdgcn_mfma_f32_16x16x32_bf16(a_l[i], b_h[j], acc[i][j], 0, 0, 0);
      }
    __syncthreads();
  }
  // epilogue: D col=lane&15, row=(lane>>4)*4+r  [m89-verified]
  #pragma unroll
  for (int i = 0; i < 4; i++)
    #pragma unroll
    for (int j = 0; j < 4; j++)
      #pragma unroll
      for (int r = 0; r < 4; r++) {
        long long grow = row0 + wr * 64 + i * 16 + (lane >> 4) * 4 + r;
        int gcol = wc * 64 + j * 16 + (lane & 15);
        if (grow < NN) h1[grow * HD + gcol] = acc[i][j][r];
      }
}

// -------- per-node attention logits, layer 1: s = h1 . a  --------
__global__ __launch_bounds__(256)
void k_s1(const float* __restrict__ h1, const float* __restrict__ as_,
          const float* __restrict__ ad_, float* __restrict__ s1s,
          float* __restrict__ s1d) {
  int w = threadIdx.x >> 6, lane = threadIdx.x & 63;
  int n = blockIdx.x * 4 + w;
  if (n >= NN) return;
  const float* hp = h1 + (size_t)n * HD;
  float h0 = hp[lane], h1v = hp[lane + 64];
  float ps = h0 * as_[lane] + h1v * as_[lane + 64];
  float pd = h0 * ad_[lane] + h1v * ad_[lane + 64];
  #pragma unroll
  for (int m = 32; m; m >>= 1) {
    ps += __shfl_xor(ps, m, 64);
    pd += __shfl_xor(pd, m, 64);
  }
  if (lane == 0) { s1s[n] = ps; s1d[n] = pd; }
}

// -------- partition pass 1: per-block LDS histogram over 391 buckets --------
// hist layout: [bucket][block]  (bucket-major for the per-bucket scan)
__global__ __launch_bounds__(256)
void k_hist(const int* __restrict__ ei, const int* __restrict__ flagp,
            int* __restrict__ hist) {
  __shared__ int cnt[NBK];
  const int flag = flagp[0];
  int b = blockIdx.x, t = threadIdx.x;
  for (int i = t; i < NBK; i += 256) cnt[i] = 0;
  __syncthreads();
  int e0 = b * CHUNK;
  int e1 = e0 + CHUNK; if (e1 > NEDGE) e1 = NEDGE;
  for (int e = e0 + t; e < e1; e += 256) {
    int s, d;
    edge_sd(ei, flag, e, s, d);
    atomicAdd(&cnt[d >> 8], 1);          // LDS atomic
  }
  __syncthreads();
  for (int i = t; i < NBK; i += 256) hist[(size_t)i * NBLK + b] = cnt[i];
}

// -------- partition pass 2a: exclusive scan of each bucket's 784 block-counts --------
__global__ __launch_bounds__(256)
void k_scanA(int* __restrict__ hist, int* __restrict__ btot) {
  __shared__ int sm[1024];
  int j = blockIdx.x, t = threadIdx.x;
  #pragma unroll
  for (int c = 0; c < 4; c++) {
    int i = t + 256 * c;
    sm[i] = (i < NBLK) ? hist[(size_t)j * NBLK + i] : 0;
  }
  __syncthreads();
  for (int d = 1; d < 1024; d <<= 1) {
    int v[4];
    #pragma unroll
    for (int c = 0; c < 4; c++) {
      int i = t + 256 * c;
      v[c] = (i >= d) ? sm[i - d] : 0;
    }
    __syncthreads();
    #pragma unroll
    for (int c = 0; c < 4; c++) sm[t + 256 * c] += v[c];
    __syncthreads();
  }
  #pragma unroll
  for (int c = 0; c < 4; c++) {
    int i = t + 256 * c;
    if (i < NBLK) hist[(size_t)j * NBLK + i] = (i == 0) ? 0 : sm[i - 1];
  }
  if (t == 0) btot[j] = sm[NBLK - 1];
}

// -------- partition pass 2b: scan bucket totals -> bbase[0..NBK] --------
__global__ __launch_bounds__(256)
void k_bscan(const int* __restrict__ btot, int* __restrict__ bbase) {
  __shared__ int sm[512];
  int t = threadIdx.x;
  for (int i = t; i < 512; i += 256) sm[i] = (i < NBK) ? btot[i] : 0;
  __syncthreads();
  for (int d = 1; d < 512; d <<= 1) {
    int v0 = (t >= d) ? sm[t - d] : 0;
    int v1 = sm[t + 256 - d];
    __syncthreads();
    sm[t] += v0;
    sm[t + 256] += v1;
    __syncthreads();
  }
  for (int i = t; i <= NBK; i += 256) bbase[i] = (i == 0) ? 0 : sm[i - 1];
}

// -------- partition pass 3: exact placement, LDS counters only --------
// pairs[pos] = src | (local_dst << 17)
__global__ __launch_bounds__(256)
void k_place(const int* __restrict__ ei, const int* __restrict__ flagp,
             const int* __restrict__ hist, const int* __restrict__ bbase,
             int* __restrict__ pairs) {
  __shared__ int ofs[NBK];
  const int flag = flagp[0];
  int b = blockIdx.x, t = threadIdx.x;
  for (int i = t; i < NBK; i += 256)
    ofs[i] = bbase[i] + hist[(size_t)i * NBLK + b];
  __syncthreads();
  int e0 = b * CHUNK;
  int e1 = e0 + CHUNK; if (e1 > NEDGE) e1 = NEDGE;
  for (int e = e0 + t; e < e1; e += 256) {
    int s, d;
    edge_sd(ei, flag, e, s, d);
    int pos = atomicAdd(&ofs[d >> 8], 1);    // LDS atomic
    pairs[pos] = s | ((d & 255) << 17);
  }
}

// -------- per-bucket CSR build: LDS count/scan/place; writes rp and adj --------
__global__ __launch_bounds__(256)
void k_part2(const int* __restrict__ pairs, const int* __restrict__ bbase,
             int* __restrict__ rp, int* __restrict__ adj) {
  __shared__ int cnt[BS], fillv[BS], wsum[4];
  int b = blockIdx.x, t = threadIdx.x;
  int n0 = b * BS;
  int j0 = bbase[b];
  int ne = bbase[b + 1] - j0;
  const int* pb = pairs + j0;
  cnt[t] = 0;
  __syncthreads();
  for (int j = t; j < ne; j += 256)
    atomicAdd(&cnt[((unsigned)pb[j]) >> 17], 1);
  __syncthreads();
  // exclusive scan over the 256 counts
  int lane = t & 63, w = t >> 6;
  int v = cnt[t];
  int xv = v;
  #pragma unroll
  for (int d = 1; d < 64; d <<= 1) {
    int y = __shfl_up(xv, d, 64);
    if (lane >= d) xv += y;
  }
  if (lane == 63) wsum[w] = xv;
  __syncthreads();
  int woff = 0;
  #pragma unroll
  for (int i = 0; i < 4; i++) if (i < w) woff += wsum[i];
  int excl = j0 + woff + xv - v;
  if (n0 + t < NN) rp[n0 + t] = excl;
  fillv[t] = excl;
  __syncthreads();
  for (int j = t; j < ne; j += 256) {
    int p = pb[j];
    int pos = atomicAdd(&fillv[((unsigned)p) >> 17], 1);
    adj[pos] = p & 0x1FFFF;
  }
  if (b == 0 && t == 0) rp[NN] = NEDGE;
}

// -------- layer-1 aggregation fused with layer-2 projection --------
// x2 = relu( (1/den) * sum_j exp(lrelu(ss[s]+sd[n])) * h1[s] + b1 )  (den inline)
// h2 = x2 @ W2 ; s2s/s2d = h2 . a2_{src,dst}     (x2 never materialized)
__global__ __launch_bounds__(256)
void k_agg1h2(const float* __restrict__ h1, const int* __restrict__ adj,
              const int* __restrict__ rp, const float* __restrict__ s1s,
              const float* __restrict__ s1d, const float* __restrict__ b1,
              const float* __restrict__ W2, const float* __restrict__ a2s,
              const float* __restrict__ a2d, float* __restrict__ h2,
              float* __restrict__ s2s, float* __restrict__ s2d) {
  __shared__ float W2T[NC * HD];     // transposed [k][f] for conflict-light f32x4 reads
  int t = threadIdx.x;
  for (int i = t; i < HD * NC; i += 256) {
    int f = i >> 3, k = i & 7;       // W2 is [f][k]
    W2T[k * HD + f] = W2[i];
  }
  __syncthreads();
  int wv = t >> 6, lane = t & 63;
  int n = blockIdx.x * 4 + wv;
  if (n >= NN) return;
  int half = lane >> 5, l32 = lane & 31;
  int j0 = rp[n], j1 = rp[n + 1];
  int deg = j1 - j0;
  int dh = (deg + 1) >> 1;
  int js = half ? (j0 + dh) : j0;
  int je = half ? j1 : (j0 + dh);
  float sdv = s1d[n];
  f32x4 acc = (f32x4){0.f, 0.f, 0.f, 0.f};
  float dsum = 0.f;
  int j = js;
  for (; j + 4 <= je; j += 4) {              // 4 gathers in flight per half-wave
    int e0 = adj[j], e1 = adj[j + 1], e2 = adj[j + 2], e3 = adj[j + 3];
    f32x4 v0 = *(const f32x4*)(h1 + (size_t)e0 * HD + l32 * 4);
    f32x4 v1 = *(const f32x4*)(h1 + (size_t)e1 * HD + l32 * 4);
    f32x4 v2 = *(const f32x4*)(h1 + (size_t)e2 * HD + l32 * 4);
    f32x4 v3 = *(const f32x4*)(h1 + (size_t)e3 * HD + l32 * 4);
    float w0 = lrelu_exp(s1s[e0] + sdv);
    float w1 = lrelu_exp(s1s[e1] + sdv);
    float w2 = lrelu_exp(s1s[e2] + sdv);
    float w3 = lrelu_exp(s1s[e3] + sdv);
    acc += w0 * v0; acc += w1 * v1; acc += w2 * v2; acc += w3 * v3;
    dsum += (w0 + w1) + (w2 + w3);
  }
  for (; j < je; ++j) {
    int e0 = adj[j];
    f32x4 v0 = *(const f32x4*)(h1 + (size_t)e0 * HD + l32 * 4);
    float w0 = lrelu_exp(s1s[e0] + sdv);
    acc += w0 * v0; dsum += w0;
  }
  // combine the two half-wave partial sums (features identical across halves)
  #pragma unroll
  for (int c = 0; c < 4; c++) acc[c] += __shfl_xor(acc[c], 32, 64);
  dsum += __shfl_xor(dsum, 32, 64);
  float inv = 1.f / (dsum + 1e-16f);
  f32x4 bv = *(const f32x4*)(b1 + l32 * 4);
  f32x4 x2v;
  #pragma unroll
  for (int c = 0; c < 4; c++) {
    float r = acc[c] * inv + bv[c];
    x2v[c] = r > 0.f ? r : 0.f;
  }
  // h2 = x2 @ W2 (per-lane 4-feature partial, then 32-lane reduce)
  float hk[NC];
  #pragma unroll
  for (int k = 0; k < NC; k++) {
    f32x4 wv4 = *(const f32x4*)&W2T[k * HD + l32 * 4];
    hk[k] = x2v[0] * wv4[0] + x2v[1] * wv4[1] + x2v[2] * wv4[2] + x2v[3] * wv4[3];
  }
  #pragma unroll
  for (int m = 1; m < 32; m <<= 1)
    #pragma unroll
    for (int k = 0; k < NC; k++) hk[k] += __shfl_xor(hk[k], m, 64);
  if (lane == 0) {
    float ss = 0.f, sd = 0.f;
    #pragma unroll
    for (int k = 0; k < NC; k++) {
      h2[(size_t)n * NC + k] = hk[k];
      ss += hk[k] * a2s[k];
      sd += hk[k] * a2d[k];
    }
    s2s[n] = ss;
    s2d[n] = sd;
  }
}

// -------- layer-2 aggregation: wave per node, 8 edges x 8 feats in flight --------
__global__ __launch_bounds__(256)
void k_agg2(const float* __restrict__ h2, const int* __restrict__ adj,
            const int* __restrict__ rp, const float* __restrict__ s2s,
            const float* __restrict__ s2d, const float* __restrict__ b2,
            float* __restrict__ out) {
  int wv = threadIdx.x >> 6, lane = threadIdx.x & 63;
  int n = blockIdx.x * 4 + wv;
  if (n >= NN) return;
  int sub = lane >> 3, k = lane & 7;
  int j0 = rp[n], j1 = rp[n + 1];
  float sdv = s2d[n];
  float a = 0.f, dsum = 0.f;
  for (int j = j0 + sub; j < j1; j += 8) {
    int s = adj[j];
    float wvv = lrelu_exp(s2s[s] + sdv);
    a += wvv * h2[(size_t)s * NC + k];
    dsum += wvv;
  }
  #pragma unroll
  for (int m = 8; m < 64; m <<= 1) {
    a += __shfl_xor(a, m, 64);
    dsum += __shfl_xor(dsum, m, 64);
  }
  if (sub == 0) out[(size_t)n * NC + k] = a / (dsum + 1e-16f) + b2[k];
}

extern "C" void kernel_launch(void* const* d_in, const int* in_sizes, int n_in,
                              void* d_out, int out_size, void* d_ws, size_t ws_size,
                              hipStream_t stream) {
  (void)in_sizes; (void)n_in; (void)out_size;
  const float* x   = (const float*)d_in[0];
  const int*   ei  = (const int*)d_in[1];
  const float* W1  = (const float*)d_in[2];
  const float* a1s = (const float*)d_in[3];
  const float* a1d = (const float*)d_in[4];
  const float* b1  = (const float*)d_in[5];
  const float* W2  = (const float*)d_in[6];
  const float* a2s = (const float*)d_in[7];
  const float* a2d = (const float*)d_in[8];
  const float* b2  = (const float*)d_in[9];
  float* out = (float*)d_out;
  char* ws = (char*)d_ws;

  // ---- workspace layout (bytes), 256-aligned ----
  size_t o = 0;
  auto take = [&](size_t bytes) { size_t c = o; o += (bytes + 255) & ~(size_t)255; return c; };
  size_t o_flag  = take(64);
  size_t o_whi   = take((size_t)HD * GKP * 2);
  size_t o_wlo   = take((size_t)HD * GKP * 2);
  size_t o_h1    = take((size_t)NN * HD * 4);
  size_t o_h2    = take((size_t)NN * NC * 4);
  size_t o_s1s   = take((size_t)NN * 4);
  size_t o_s1d   = take((size_t)NN * 4);
  size_t o_s2s   = take((size_t)NN * 4);
  size_t o_s2d   = take((size_t)NN * 4);
  size_t o_rp    = take((size_t)(NN + 1) * 4);
  size_t o_adj   = take((size_t)NEDGE * 4);
  size_t o_pairs = take((size_t)NEDGE * 4);
  size_t o_hist  = take((size_t)NBK * NBLK * 4);
  size_t o_btot  = take((size_t)NBK * 4);
  size_t o_bbase = take((size_t)(NBK + 1) * 4);
  if (o > ws_size) return;                        // workspace too small -> loud failure

  int*   flag = (int*)(ws + o_flag);
  ushort_t* whi = (ushort_t*)(ws + o_whi);
  ushort_t* wlo = (ushort_t*)(ws + o_wlo);
  float* h1  = (float*)(ws + o_h1);
  float* h2  = (float*)(ws + o_h2);
  float* s1s = (float*)(ws + o_s1s);
  float* s1d = (float*)(ws + o_s1d);
  float* s2s = (float*)(ws + o_s2s);
  float* s2d = (float*)(ws + o_s2d);
  int* rp    = (int*)(ws + o_rp);
  int* adj   = (int*)(ws + o_adj);
  int* pairs = (int*)(ws + o_pairs);
  int* hist  = (int*)(ws + o_hist);
  int* btot  = (int*)(ws + o_btot);
  int* bbase = (int*)(ws + o_bbase);

  k_detect<<<1, 64, 0, stream>>>(ei, flag);
  k_prepw1<<<(HD * GKP + 255) / 256, 256, 0, stream>>>(W1, whi, wlo);
  k_gemm1<<<(NN + 127) / 128, 256, 0, stream>>>(x, whi, wlo, h1);
  k_s1<<<(NN + 3) / 4, 256, 0, stream>>>(h1, a1s, a1d, s1s, s1d);
  k_hist<<<NBLK, 256, 0, stream>>>(ei, flag, hist);
  k_scanA<<<NBK, 256, 0, stream>>>(hist, btot);
  k_bscan<<<1, 256, 0, stream>>>(btot, bbase);
  k_place<<<NBLK, 256, 0, stream>>>(ei, flag, hist, bbase, pairs);
  k_part2<<<NBK, 256, 0, stream>>>(pairs, bbase, rp, adj);
  k_agg1h2<<<(NN + 3) / 4, 256, 0, stream>>>(h1, adj, rp, s1s, s1d, b1, W2,
                                             a2s, a2d, h2, s2s, s2d);
  k_agg2<<<(NN + 3) / 4, 256, 0, stream>>>(h2, adj, rp, s2s, s2d, b2, out);
}

// Round 6
// 791.587 us; speedup vs baseline: 2.5724x; 1.1261x over previous
//
#include <hip/hip_runtime.h>
#include <stdint.h>

// ---------------- problem constants ----------------
#define NN 100000          // nodes
#define EE 3200000         // raw edges
#define NEDGE (EE + NN)    // + self loops
#define KD 745             // F_IN
#define GKP 768            // K padded to mult of 32
#define HD 128             // hidden
#define NC 8               // classes
#define HDP 132            // padded W2T row

// partition params
#define BS 256                       // nodes per bucket
#define NBK 391                      // ceil(NN/BS)
#define NBLK 784                     // histogram/placement blocks
#define CHUNK ((NEDGE + NBLK - 1) / NBLK)

typedef unsigned short ushort_t;
typedef __attribute__((ext_vector_type(8))) short short8;
typedef __attribute__((ext_vector_type(4))) float f32x4;
typedef __attribute__((ext_vector_type(4))) ushort_t ushort4_t;

__device__ __forceinline__ ushort_t f2bf(float f) {
  unsigned int u = __float_as_uint(f);
  u += 0x7FFFu + ((u >> 16) & 1u);     // RNE
  return (ushort_t)(u >> 16);
}
__device__ __forceinline__ float bf2f(ushort_t h) {
  return __uint_as_float(((unsigned int)h) << 16);
}
__device__ __forceinline__ float lrelu_exp(float t) {
  return __expf(t >= 0.f ? t : 0.2f * t);
}

// -------- detect whether edge_index arrived as int64 (odd int32 words all 0) --------
__global__ void k_detect(const int* __restrict__ ei, int* __restrict__ flag) {
  if (threadIdx.x == 0) {
    int orv = 0;
    #pragma unroll
    for (int i = 0; i < 16; i++) orv |= ei[2 * i + 1];
    flag[0] = (orv == 0) ? 1 : 0;
  }
}

__device__ __forceinline__ void edge_sd(const int* __restrict__ ei, int flag, int e,
                                        int& s, int& d) {
  if (e < EE) {
    if (flag) {
      s = ((const int2*)ei)[e].x;
      d = ((const int2*)ei)[EE + e].x;
    } else {
      s = ei[e];
      d = ei[EE + e];
    }
  } else { s = e - EE; d = s; }
}

// -------- W1 -> transposed bf16 hi/lo, K padded to 768 --------
__global__ __launch_bounds__(256)
void k_prepw1(const float* __restrict__ W1, ushort_t* __restrict__ WhiT,
              ushort_t* __restrict__ WloT) {
  int idx = blockIdx.x * 256 + threadIdx.x;       // 128*768 total
  if (idx >= HD * GKP) return;
  int n = idx / GKP, k = idx % GKP;
  float v = (k < KD) ? W1[(size_t)k * HD + n] : 0.f;
  ushort_t hi = f2bf(v);
  ushort_t lo = f2bf(v - bf2f(hi));
  WhiT[(size_t)n * GKP + k] = hi;
  WloT[(size_t)n * GKP + k] = lo;
}

// -------- GEMM1 + fused s1: h1b[N,128] (bf16) = x @ W1 ; s1s/s1d from fp32 acc --------
__global__ __launch_bounds__(256, 2)
void k_gemm1(const float* __restrict__ x, const ushort_t* __restrict__ WhiT,
             const ushort_t* __restrict__ WloT, const float* __restrict__ a1s,
             const float* __restrict__ a1d, ushort_t* __restrict__ h1b,
             float* __restrict__ s1s, float* __restrict__ s1d) {
  __shared__ ushort_t Ah[128 * 32], Al[128 * 32], Bh[128 * 32], Bl[128 * 32];
  __shared__ float sred[128][4];                  // [row][wc | 2+wc] = {ps, pd}
  const int tid = threadIdx.x;
  const int lane = tid & 63;
  const int wid = tid >> 6;
  const int wr = wid >> 1, wc = wid & 1;          // 2x2 waves over 128x128 tile
  const long long row0 = (long long)blockIdx.x * 128;
  const int am = tid >> 1, ah = tid & 1;          // A stage: row am, 16 floats

  f32x4 acc[4][4];
  #pragma unroll
  for (int i = 0; i < 4; i++)
    #pragma unroll
    for (int j = 0; j < 4; j++) acc[i][j] = (f32x4){0.f, 0.f, 0.f, 0.f};

  for (int k0 = 0; k0 < GKP; k0 += 32) {
    // ---- stage A (fp32 -> bf16 hi/lo) ----
    {
      long long gr = row0 + am;
      int kb = k0 + ah * 16;
      float v[16];
      if (gr < NN && kb + 16 <= KD) {
        const float* xp = x + gr * KD + kb;
        #pragma unroll
        for (int i = 0; i < 16; i++) v[i] = xp[i];
      } else if (gr < NN) {
        const float* xp = x + gr * KD + kb;
        #pragma unroll
        for (int i = 0; i < 16; i++) v[i] = (kb + i < KD) ? xp[i] : 0.f;
      } else {
        #pragma unroll
        for (int i = 0; i < 16; i++) v[i] = 0.f;
      }
      ushort_t* ph = &Ah[am * 32 + ah * 16];
      ushort_t* pl = &Al[am * 32 + ah * 16];
      #pragma unroll
      for (int i = 0; i < 16; i++) {
        ushort_t hi = f2bf(v[i]);
        ph[i] = hi;
        pl[i] = f2bf(v[i] - bf2f(hi));
      }
    }
    // ---- stage B (already bf16, [n][k] rows) ----
    {
      const int bn = tid >> 1, off = (tid & 1) * 16;
      const ushort_t* gh = WhiT + (size_t)bn * GKP + k0 + off;
      const ushort_t* gl = WloT + (size_t)bn * GKP + k0 + off;
      ushort_t* dh = &Bh[bn * 32 + off];
      ushort_t* dl = &Bl[bn * 32 + off];
      *(short8*)dh = *(const short8*)gh;
      *(short8*)(dh + 8) = *(const short8*)(gh + 8);
      *(short8*)dl = *(const short8*)gl;
      *(short8*)(dl + 8) = *(const short8*)(gl + 8);
    }
    __syncthreads();

    const int rr = lane & 15, kk = (lane >> 4) * 8;
    short8 a_h[4], a_l[4], b_h[4], b_l[4];
    #pragma unroll
    for (int i = 0; i < 4; i++) {
      a_h[i] = *(const short8*)&Ah[(wr * 64 + i * 16 + rr) * 32 + kk];
      a_l[i] = *(const short8*)&Al[(wr * 64 + i * 16 + rr) * 32 + kk];
      b_h[i] = *(const short8*)&Bh[(wc * 64 + i * 16 + rr) * 32 + kk];
      b_l[i] = *(const short8*)&Bl[(wc * 64 + i * 16 + rr) * 32 + kk];
    }
    #pragma unroll
    for (int i = 0; i < 4; i++)
      #pragma unroll
      for (int j = 0; j < 4; j++) {
        acc[i][j] = __builtin_amdgcn_mfma_f32_16x16x32_bf16(a_h[i], b_h[j], acc[i][j], 0, 0, 0);
        acc[i][j] = __builtin_amdgcn_mfma_f32_16x16x32_bf16(a_h[i], b_l[j], acc[i][j], 0, 0, 0);
        acc[i][j] = __builtin_amdgcn_mfma_f32_16x16x32_bf16(a_l[i], b_h[j], acc[i][j], 0, 0, 0);
      }
    __syncthreads();
  }

  // ---- epilogue: bf16 h1 store + fused s1 ----
  // D layout: col=lane&15, row=(lane>>4)*4+r  [m89-verified]
  const int cl = lane & 15, gq = lane >> 4;
  float avS[4], avD[4];                 // a1 at this lane's 4 possible cols
  #pragma unroll
  for (int j = 0; j < 4; j++) {
    avS[j] = a1s[wc * 64 + j * 16 + cl];
    avD[j] = a1d[wc * 64 + j * 16 + cl];
  }
  #pragma unroll
  for (int i = 0; i < 4; i++)
    #pragma unroll
    for (int r = 0; r < 4; r++) {
      long long grow = row0 + wr * 64 + i * 16 + gq * 4 + r;
      float ps = 0.f, pd = 0.f;
      #pragma unroll
      for (int j = 0; j < 4; j++) {
        float hv = acc[i][j][r];
        ps += hv * avS[j];
        pd += hv * avD[j];
        if (grow < NN)
          h1b[grow * HD + wc * 64 + j * 16 + cl] = f2bf(hv);
      }
      // reduce across the 16 lanes sharing this row
      #pragma unroll
      for (int m = 1; m < 16; m <<= 1) {
        ps += __shfl_xor(ps, m, 64);
        pd += __shfl_xor(pd, m, 64);
      }
      if (cl == 0) {
        int lrow = wr * 64 + i * 16 + gq * 4 + r;
        sred[lrow][wc] = ps;
        sred[lrow][2 + wc] = pd;
      }
    }
  __syncthreads();
  if (tid < 128) {
    long long grow = row0 + tid;
    if (grow < NN) {
      s1s[grow] = sred[tid][0] + sred[tid][1];
      s1d[grow] = sred[tid][2] + sred[tid][3];
    }
  }
}

// -------- partition pass 1: per-block LDS histogram over 391 buckets --------
// hist layout: [bucket][block]  (bucket-major for the per-bucket scan)
__global__ __launch_bounds__(256)
void k_hist(const int* __restrict__ ei, const int* __restrict__ flagp,
            int* __restrict__ hist) {
  __shared__ int cnt[NBK];
  const int flag = flagp[0];
  int b = blockIdx.x, t = threadIdx.x;
  for (int i = t; i < NBK; i += 256) cnt[i] = 0;
  __syncthreads();
  int e0 = b * CHUNK;
  int e1 = e0 + CHUNK; if (e1 > NEDGE) e1 = NEDGE;
  for (int e = e0 + t; e < e1; e += 256) {
    int s, d;
    edge_sd(ei, flag, e, s, d);
    atomicAdd(&cnt[d >> 8], 1);          // LDS atomic
  }
  __syncthreads();
  for (int i = t; i < NBK; i += 256) hist[(size_t)i * NBLK + b] = cnt[i];
}

// -------- partition pass 2a: exclusive scan of each bucket's 784 block-counts --------
__global__ __launch_bounds__(256)
void k_scanA(int* __restrict__ hist, int* __restrict__ btot) {
  __shared__ int sm[1024];
  int j = blockIdx.x, t = threadIdx.x;
  #pragma unroll
  for (int c = 0; c < 4; c++) {
    int i = t + 256 * c;
    sm[i] = (i < NBLK) ? hist[(size_t)j * NBLK + i] : 0;
  }
  __syncthreads();
  for (int d = 1; d < 1024; d <<= 1) {
    int v[4];
    #pragma unroll
    for (int c = 0; c < 4; c++) {
      int i = t + 256 * c;
      v[c] = (i >= d) ? sm[i - d] : 0;
    }
    __syncthreads();
    #pragma unroll
    for (int c = 0; c < 4; c++) sm[t + 256 * c] += v[c];
    __syncthreads();
  }
  #pragma unroll
  for (int c = 0; c < 4; c++) {
    int i = t + 256 * c;
    if (i < NBLK) hist[(size_t)j * NBLK + i] = (i == 0) ? 0 : sm[i - 1];
  }
  if (t == 0) btot[j] = sm[NBLK - 1];
}

// -------- partition pass 2b: scan bucket totals -> bbase[0..NBK] --------
__global__ __launch_bounds__(256)
void k_bscan(const int* __restrict__ btot, int* __restrict__ bbase) {
  __shared__ int sm[512];
  int t = threadIdx.x;
  for (int i = t; i < 512; i += 256) sm[i] = (i < NBK) ? btot[i] : 0;
  __syncthreads();
  for (int d = 1; d < 512; d <<= 1) {
    int v0 = (t >= d) ? sm[t - d] : 0;
    int v1 = sm[t + 256 - d];
    __syncthreads();
    sm[t] += v0;
    sm[t + 256] += v1;
    __syncthreads();
  }
  for (int i = t; i <= NBK; i += 256) bbase[i] = (i == 0) ? 0 : sm[i - 1];
}

// -------- partition pass 3: exact placement, LDS counters only --------
// pairs[pos] = src | (local_dst << 17)
__global__ __launch_bounds__(256)
void k_place(const int* __restrict__ ei, const int* __restrict__ flagp,
             const int* __restrict__ hist, const int* __restrict__ bbase,
             int* __restrict__ pairs) {
  __shared__ int ofs[NBK];
  const int flag = flagp[0];
  int b = blockIdx.x, t = threadIdx.x;
  for (int i = t; i < NBK; i += 256)
    ofs[i] = bbase[i] + hist[(size_t)i * NBLK + b];
  __syncthreads();
  int e0 = b * CHUNK;
  int e1 = e0 + CHUNK; if (e1 > NEDGE) e1 = NEDGE;
  for (int e = e0 + t; e < e1; e += 256) {
    int s, d;
    edge_sd(ei, flag, e, s, d);
    int pos = atomicAdd(&ofs[d >> 8], 1);    // LDS atomic
    pairs[pos] = s | ((d & 255) << 17);
  }
}

// -------- per-bucket CSR build: LDS count/scan/place; writes rp and adj --------
__global__ __launch_bounds__(256)
void k_part2(const int* __restrict__ pairs, const int* __restrict__ bbase,
             int* __restrict__ rp, int* __restrict__ adj) {
  __shared__ int cnt[BS], fillv[BS], wsum[4];
  int b = blockIdx.x, t = threadIdx.x;
  int n0 = b * BS;
  int j0 = bbase[b];
  int ne = bbase[b + 1] - j0;
  const int* pb = pairs + j0;
  cnt[t] = 0;
  __syncthreads();
  for (int j = t; j < ne; j += 256)
    atomicAdd(&cnt[((unsigned)pb[j]) >> 17], 1);
  __syncthreads();
  // exclusive scan over the 256 counts
  int lane = t & 63, w = t >> 6;
  int v = cnt[t];
  int xv = v;
  #pragma unroll
  for (int d = 1; d < 64; d <<= 1) {
    int y = __shfl_up(xv, d, 64);
    if (lane >= d) xv += y;
  }
  if (lane == 63) wsum[w] = xv;
  __syncthreads();
  int woff = 0;
  #pragma unroll
  for (int i = 0; i < 4; i++) if (i < w) woff += wsum[i];
  int excl = j0 + woff + xv - v;
  if (n0 + t < NN) rp[n0 + t] = excl;
  fillv[t] = excl;
  __syncthreads();
  for (int j = t; j < ne; j += 256) {
    int p = pb[j];
    int pos = atomicAdd(&fillv[((unsigned)p) >> 17], 1);
    adj[pos] = p & 0x1FFFF;
  }
  if (b == 0 && t == 0) rp[NN] = NEDGE;
}

// -------- layer-1 aggregation (bf16 h1 gather) fused with layer-2 projection --------
__global__ __launch_bounds__(256)
void k_agg1h2(const ushort_t* __restrict__ h1b, const int* __restrict__ adj,
              const int* __restrict__ rp, const float* __restrict__ s1s,
              const float* __restrict__ s1d, const float* __restrict__ b1,
              const float* __restrict__ W2, const float* __restrict__ a2s,
              const float* __restrict__ a2d, float* __restrict__ h2,
              float* __restrict__ s2s, float* __restrict__ s2d) {
  __shared__ float W2T[NC * HDP];    // transposed [k][f], padded
  int t = threadIdx.x;
  for (int i = t; i < HD * NC; i += 256) {
    int f = i >> 3, k = i & 7;       // W2 is [f][k]
    W2T[k * HDP + f] = W2[i];
  }
  __syncthreads();
  int wv = t >> 6, lane = t & 63;
  int n = blockIdx.x * 4 + wv;
  if (n >= NN) return;
  int half = lane >> 5, l32 = lane & 31;
  int j0 = rp[n], j1 = rp[n + 1];
  int deg = j1 - j0;
  int dh = (deg + 1) >> 1;
  int js = half ? (j0 + dh) : j0;
  int je = half ? j1 : (j0 + dh);
  float sdv = s1d[n];
  f32x4 acc = (f32x4){0.f, 0.f, 0.f, 0.f};
  float dsum = 0.f;
  int j = js;
  for (; j + 8 <= je; j += 8) {              // 8 gathers in flight per half-wave
    int e[8];
    ushort4_t u[8];
    float w[8];
    #pragma unroll
    for (int q = 0; q < 8; q++) e[q] = adj[j + q];
    #pragma unroll
    for (int q = 0; q < 8; q++)
      u[q] = *(const ushort4_t*)(h1b + (size_t)e[q] * HD + l32 * 4);
    #pragma unroll
    for (int q = 0; q < 8; q++) w[q] = lrelu_exp(s1s[e[q]] + sdv);
    #pragma unroll
    for (int q = 0; q < 8; q++) {
      acc[0] += w[q] * bf2f(u[q][0]);
      acc[1] += w[q] * bf2f(u[q][1]);
      acc[2] += w[q] * bf2f(u[q][2]);
      acc[3] += w[q] * bf2f(u[q][3]);
      dsum += w[q];
    }
  }
  for (; j < je; ++j) {
    int e0 = adj[j];
    ushort4_t u = *(const ushort4_t*)(h1b + (size_t)e0 * HD + l32 * 4);
    float w0 = lrelu_exp(s1s[e0] + sdv);
    acc[0] += w0 * bf2f(u[0]);
    acc[1] += w0 * bf2f(u[1]);
    acc[2] += w0 * bf2f(u[2]);
    acc[3] += w0 * bf2f(u[3]);
    dsum += w0;
  }
  // combine the two half-wave partial sums (features identical across halves)
  #pragma unroll
  for (int c = 0; c < 4; c++) acc[c] += __shfl_xor(acc[c], 32, 64);
  dsum += __shfl_xor(dsum, 32, 64);
  float inv = 1.f / (dsum + 1e-16f);
  f32x4 bv = *(const f32x4*)(b1 + l32 * 4);
  f32x4 x2v;
  #pragma unroll
  for (int c = 0; c < 4; c++) {
    float r = acc[c] * inv + bv[c];
    x2v[c] = r > 0.f ? r : 0.f;
  }
  // h2 = x2 @ W2 (per-lane 4-feature partial, then 32-lane reduce)
  float hk[NC];
  #pragma unroll
  for (int k = 0; k < NC; k++) {
    const float* wp = &W2T[k * HDP + l32 * 4];
    hk[k] = x2v[0] * wp[0] + x2v[1] * wp[1] + x2v[2] * wp[2] + x2v[3] * wp[3];
  }
  #pragma unroll
  for (int m = 1; m < 32; m <<= 1)
    #pragma unroll
    for (int k = 0; k < NC; k++) hk[k] += __shfl_xor(hk[k], m, 64);
  if (lane == 0) {
    float ss = 0.f, sd = 0.f;
    #pragma unroll
    for (int k = 0; k < NC; k++) {
      h2[(size_t)n * NC + k] = hk[k];
      ss += hk[k] * a2s[k];
      sd += hk[k] * a2d[k];
    }
    s2s[n] = ss;
    s2d[n] = sd;
  }
}

// -------- layer-2 aggregation: wave per node, 8 edges x 8 feats in flight --------
__global__ __launch_bounds__(256)
void k_agg2(const float* __restrict__ h2, const int* __restrict__ adj,
            const int* __restrict__ rp, const float* __restrict__ s2s,
            const float* __restrict__ s2d, const float* __restrict__ b2,
            float* __restrict__ out) {
  int wv = threadIdx.x >> 6, lane = threadIdx.x & 63;
  int n = blockIdx.x * 4 + wv;
  if (n >= NN) return;
  int sub = lane >> 3, k = lane & 7;
  int j0 = rp[n], j1 = rp[n + 1];
  float sdv = s2d[n];
  float a = 0.f, dsum = 0.f;
  for (int j = j0 + sub; j < j1; j += 8) {
    int s = adj[j];
    float wvv = lrelu_exp(s2s[s] + sdv);
    a += wvv * h2[(size_t)s * NC + k];
    dsum += wvv;
  }
  #pragma unroll
  for (int m = 8; m < 64; m <<= 1) {
    a += __shfl_xor(a, m, 64);
    dsum += __shfl_xor(dsum, m, 64);
  }
  if (sub == 0) out[(size_t)n * NC + k] = a / (dsum + 1e-16f) + b2[k];
}

extern "C" void kernel_launch(void* const* d_in, const int* in_sizes, int n_in,
                              void* d_out, int out_size, void* d_ws, size_t ws_size,
                              hipStream_t stream) {
  (void)in_sizes; (void)n_in; (void)out_size;
  const float* x   = (const float*)d_in[0];
  const int*   ei  = (const int*)d_in[1];
  const float* W1  = (const float*)d_in[2];
  const float* a1s = (const float*)d_in[3];
  const float* a1d = (const float*)d_in[4];
  const float* b1  = (const float*)d_in[5];
  const float* W2  = (const float*)d_in[6];
  const float* a2s = (const float*)d_in[7];
  const float* a2d = (const float*)d_in[8];
  const float* b2  = (const float*)d_in[9];
  float* out = (float*)d_out;
  char* ws = (char*)d_ws;

  // ---- workspace layout (bytes), 256-aligned ----
  size_t o = 0;
  auto take = [&](size_t bytes) { size_t c = o; o += (bytes + 255) & ~(size_t)255; return c; };
  size_t o_flag  = take(64);
  size_t o_whi   = take((size_t)HD * GKP * 2);
  size_t o_wlo   = take((size_t)HD * GKP * 2);
  size_t o_h1    = take((size_t)NN * HD * 2);     // bf16 now
  size_t o_h2    = take((size_t)NN * NC * 4);
  size_t o_s1s   = take((size_t)NN * 4);
  size_t o_s1d   = take((size_t)NN * 4);
  size_t o_s2s   = take((size_t)NN * 4);
  size_t o_s2d   = take((size_t)NN * 4);
  size_t o_rp    = take((size_t)(NN + 1) * 4);
  size_t o_adj   = take((size_t)NEDGE * 4);
  size_t o_pairs = take((size_t)NEDGE * 4);
  size_t o_hist  = take((size_t)NBK * NBLK * 4);
  size_t o_btot  = take((size_t)NBK * 4);
  size_t o_bbase = take((size_t)(NBK + 1) * 4);
  if (o > ws_size) return;                        // workspace too small -> loud failure

  int*   flag = (int*)(ws + o_flag);
  ushort_t* whi = (ushort_t*)(ws + o_whi);
  ushort_t* wlo = (ushort_t*)(ws + o_wlo);
  ushort_t* h1b = (ushort_t*)(ws + o_h1);
  float* h2  = (float*)(ws + o_h2);
  float* s1s = (float*)(ws + o_s1s);
  float* s1d = (float*)(ws + o_s1d);
  float* s2s = (float*)(ws + o_s2s);
  float* s2d = (float*)(ws + o_s2d);
  int* rp    = (int*)(ws + o_rp);
  int* adj   = (int*)(ws + o_adj);
  int* pairs = (int*)(ws + o_pairs);
  int* hist  = (int*)(ws + o_hist);
  int* btot  = (int*)(ws + o_btot);
  int* bbase = (int*)(ws + o_bbase);

  k_detect<<<1, 64, 0, stream>>>(ei, flag);
  k_prepw1<<<(HD * GKP + 255) / 256, 256, 0, stream>>>(W1, whi, wlo);
  k_gemm1<<<(NN + 127) / 128, 256, 0, stream>>>(x, whi, wlo, a1s, a1d, h1b, s1s, s1d);
  k_hist<<<NBLK, 256, 0, stream>>>(ei, flag, hist);
  k_scanA<<<NBK, 256, 0, stream>>>(hist, btot);
  k_bscan<<<1, 256, 0, stream>>>(btot, bbase);
  k_place<<<NBLK, 256, 0, stream>>>(ei, flag, hist, bbase, pairs);
  k_part2<<<NBK, 256, 0, stream>>>(pairs, bbase, rp, adj);
  k_agg1h2<<<(NN + 3) / 4, 256, 0, stream>>>(h1b, adj, rp, s1s, s1d, b1, W2,
                                             a2s, a2d, h2, s2s, s2d);
  k_agg2<<<(NN + 3) / 4, 256, 0, stream>>>(h2, adj, rp, s2s, s2d, b2, out);
}